// Round 13
// baseline (270.601 us; speedup 1.0000x reference)
//
#include <hip/hip_runtime.h>
#include <hip/hip_bf16.h>

#define B_ 64
#define S_ 1024
#define H_ 256
#define E_ 256

#define EG_ 32          // e-columns per k2 block (proven best, R10/R12)
#define LDSB_ST 264     // bf16 stride for B panel rows
#define CH_ 128         // rows per s-chunk (8 waves x 16)
#define NCH_ 8          // s-chunks per batch
#define STG_ST 34       // per-wave staging row stride (floats): <=2-way conflicts

typedef __attribute__((ext_vector_type(8))) __bf16 bf16x8;
typedef __attribute__((ext_vector_type(4))) __bf16 bf16x4;
typedef __attribute__((ext_vector_type(4))) float f32x4;

// ---- k0: blk<512 -> w[m]=exp(alpha.Wa+ba)*mask (16-lane coalesced, verified)
//          + Wb fp32->bf16 on blk<64;  blk>=512 -> beta fp32->bf16 streaming.
__global__ __launch_bounds__(256) void k0_prep(
        const float* __restrict__ alpha, const float* __restrict__ mask,
        const float* __restrict__ Wa,    const float* __restrict__ ba,
        const float* __restrict__ Wb,    const float* __restrict__ beta,
        __bf16* __restrict__ WbBf,       __bf16* __restrict__ betaBf,
        float* __restrict__ w) {
    const int tid = threadIdx.x, blk = blockIdx.x;
    if (blk >= 512) {                 // beta convert: 512 blocks x 256 thr x 32 f4
        const int base = (blk - 512) * 256 + tid;
        #pragma unroll 4
        for (int i = 0; i < 32; ++i) {
            const int idx = base + i * 131072;
            float4 v = ((const float4*)beta)[idx];
            bf16x4 bv;
            bv[0]=(__bf16)v.x; bv[1]=(__bf16)v.y; bv[2]=(__bf16)v.z; bv[3]=(__bf16)v.w;
            ((bf16x4*)betaBf)[idx] = bv;
        }
        return;
    }
    if (blk < 64) {
        int i = blk * 256 + tid;
        float4 v = ((const float4*)Wb)[i];
        bf16x4 bv;
        bv[0]=(__bf16)v.x; bv[1]=(__bf16)v.y; bv[2]=(__bf16)v.z; bv[3]=(__bf16)v.w;
        ((bf16x4*)WbBf)[i] = bv;
    }
    const int wv = tid >> 6, lane = tid & 63;
    const int rsub = lane >> 4, pcl = lane & 15;
    const float4* Wa4 = (const float4*)Wa;
    float4 wa0 = Wa4[pcl], wa1 = Wa4[pcl + 16],
           wa2 = Wa4[pcl + 32], wa3 = Wa4[pcl + 48];
    const float ba0 = ba[0];
    #pragma unroll 2
    for (int ps = 0; ps < 8; ++ps) {
        const int m = blk * 128 + ps * 16 + wv * 4 + rsub;
        const float4* ap = (const float4*)(alpha + (size_t)m * H_);
        float4 x0 = ap[pcl], x1 = ap[pcl + 16], x2 = ap[pcl + 32], x3 = ap[pcl + 48];
        float p = x0.x*wa0.x + x0.y*wa0.y + x0.z*wa0.z + x0.w*wa0.w
                + x1.x*wa1.x + x1.y*wa1.y + x1.z*wa1.z + x1.w*wa1.w
                + x2.x*wa2.x + x2.y*wa2.y + x2.z*wa2.z + x2.w*wa2.w
                + x3.x*wa3.x + x3.y*wa3.y + x3.z*wa3.z + x3.w*wa3.w;
        p += __shfl_xor(p, 1, 64);
        p += __shfl_xor(p, 2, 64);
        p += __shfl_xor(p, 4, 64);
        p += __shfl_xor(p, 8, 64);
        if (pcl == 0) w[m] = __expf(p + ba0) * mask[m];
    }
}

// ---- k2_bf: R12 + epilogue LDS-coalescing.
//  Embed in:  2x dwordx4/lane -> wave-private stg -> 8 scalar ds_reads.
//  t out:     8 scalar ds_writes -> stg -> 2x dwordx4 coalesced stores.
//  VMEM ops/chunk/thread: 24 -> 12. Everything else identical to R12.
__global__ __launch_bounds__(512, 4) void k2_bf(
        const __bf16* __restrict__ betaBf, const float* __restrict__ embed,
        const __bf16* __restrict__ WbBf,   const float* __restrict__ bb,
        const float* __restrict__ w,       float* __restrict__ t) {
    __shared__ __bf16 ldsB[EG_ * LDSB_ST];   // 16.5 KB stationary B panel
    __shared__ float wsLds[S_];              // w[b, :]
    __shared__ float ivLds[S_];              // 1/(w-suffix + eps)
    __shared__ float red[2][8 * EG_];        // dbuf per-wave column totals
    __shared__ float run[2][EG_];            // dbuf cross-chunk carry
    __shared__ float wsum[4];
    __shared__ float stg[8][16][STG_ST];     // 17.4 KB wave-private transit

    const int tid = threadIdx.x;
    const int wv = tid >> 6, lane = tid & 63;
    const int l15 = lane & 15, q = lane >> 4;
    const int l7 = lane & 7,  r8 = lane >> 3;   // embed-stage mapping
    const int orow = lane >> 2, oc8 = (lane & 3) * 8;  // output mapping
    const int blk = blockIdx.x;
    // XCD co-location: 8 e-group blocks of a batch share blk%8 -> one XCD L2
    const int b  = (blk & 7) * 8 + (blk >> 6);
    const int eg = (blk >> 3) & 7;

    {   // stage B panel + w
        const int e = tid >> 4, kq = (tid & 15) * 16;
        const __bf16* src = WbBf + (size_t)(eg * EG_ + e) * H_ + kq;
        *(bf16x8*)(ldsB + e * LDSB_ST + kq)     = *(const bf16x8*)(src);
        *(bf16x8*)(ldsB + e * LDSB_ST + kq + 8) = *(const bf16x8*)(src + 8);
    }
    if (tid < 256)
        *(float4*)(wsLds + tid * 4) = *(const float4*)(w + b * S_ + tid * 4);
    if (tid < 64) run[tid >> 5][tid & 31] = 0.f;
    __syncthreads();

    {   // in-LDS suffix scan of w -> ivLds (verified R5/R10)
        float w0 = 0, w1 = 0, w2 = 0, w3 = 0, tot = 0, suf = 0;
        const int sl = tid & 63, sw = tid >> 6;
        if (tid < 256) {
            w0 = wsLds[tid * 4];     w1 = wsLds[tid * 4 + 1];
            w2 = wsLds[tid * 4 + 2]; w3 = wsLds[tid * 4 + 3];
            tot = w0 + w1 + w2 + w3;
            suf = tot;
            #pragma unroll
            for (int off = 1; off < 64; off <<= 1) {
                float o = __shfl_down(suf, off, 64);
                if (sl + off < 64) suf += o;
            }
            if (sl == 0) wsum[sw] = suf;
        }
        __syncthreads();
        if (tid < 256) {
            float waveOff = 0.f;
            for (int j = sw + 1; j < 4; ++j) waveOff += wsum[j];
            float after = (suf - tot) + waveOff;
            float s3 = w3 + after, s2 = w2 + s3, s1 = w1 + s2, s0 = w0 + s1;
            ivLds[tid * 4]     = 1.f / (s0 + 1e-10f);
            ivLds[tid * 4 + 1] = 1.f / (s1 + 1e-10f);
            ivLds[tid * 4 + 2] = 1.f / (s2 + 1e-10f);
            ivLds[tid * 4 + 3] = 1.f / (s3 + 1e-10f);
        }
        __syncthreads();
    }

    const float bb0 = bb[eg * EG_ + l15];
    const float bb1 = bb[eg * EG_ + 16 + l15];
    const __bf16* Abase = betaBf + ((size_t)b * S_ + wv * 16 + l15) * H_ + q * 8;
    const float* Eg = embed + ((size_t)b * S_ + wv * 16) * E_ + eg * EG_;
    float*       Tg = t     + ((size_t)b * S_ + wv * 16) * E_ + eg * EG_;

    // prologue: prefetch chunk 7's A fragments and embed tile (coalesced f4)
    bf16x8 nA[8];
    float4 eF0, eF1;
    {
        const size_t coff = (size_t)(NCH_ - 1) * CH_ * H_;
        #pragma unroll
        for (int kc = 0; kc < 8; ++kc)
            nA[kc] = *(const bf16x8*)(Abase + coff + (size_t)kc * 32);
        eF0 = *(const float4*)(Eg + ((size_t)(NCH_ - 1) * CH_ + r8) * E_ + l7 * 4);
        eF1 = *(const float4*)(Eg + ((size_t)(NCH_ - 1) * CH_ + 8 + r8) * E_ + l7 * 4);
    }

    #pragma unroll
    for (int si = 0; si < 8; ++si) {
        const int c = 7 - si;
        const int rb = si & 1;

        bf16x8 curA[8];                 // SSA renames of landed prefetches
        #pragma unroll
        for (int kc = 0; kc < 8; ++kc) curA[kc] = nA[kc];
        float4 eW0 = eF0, eW1 = eF1;

        // NEXT-chunk A + embed prefetch, issued BEFORE everything else
        if (c > 0) {
            const size_t poff = (size_t)(c - 1) * CH_ * H_;
            #pragma unroll
            for (int kc = 0; kc < 8; ++kc)
                nA[kc] = *(const bf16x8*)(Abase + poff + (size_t)kc * 32);
            eF0 = *(const float4*)(Eg + ((size_t)(c - 1) * CH_ + r8) * E_ + l7 * 4);
            eF1 = *(const float4*)(Eg + ((size_t)(c - 1) * CH_ + 8 + r8) * E_ + l7 * 4);
        }

        // stage this chunk's embed tile (loaded last iteration) -> wave-private
        *(float4*)(&stg[wv][r8][l7 * 4])     = eW0;
        *(float4*)(&stg[wv][8 + r8][l7 * 4]) = eW1;
        asm volatile("s_waitcnt lgkmcnt(0)" ::: "memory");
        float eUse0[4], eUse1[4];
        #pragma unroll
        for (int r = 0; r < 4; ++r) {
            eUse0[r] = stg[wv][q * 4 + r][l15];
            eUse1[r] = stg[wv][q * 4 + r][16 + l15];
        }

        f32x4 acc0 = {0.f, 0.f, 0.f, 0.f}, acc1 = {0.f, 0.f, 0.f, 0.f};
        #pragma unroll
        for (int kc = 0; kc < 8; ++kc) {
            bf16x8 bf0 = *(const bf16x8*)(ldsB + l15 * LDSB_ST + kc * 32 + q * 8);
            bf16x8 bf1 = *(const bf16x8*)(ldsB + (16 + l15) * LDSB_ST + kc * 32 + q * 8);
            acc0 = __builtin_amdgcn_mfma_f32_16x16x32_bf16(curA[kc], bf0, acc0, 0, 0, 0);
            acc1 = __builtin_amdgcn_mfma_f32_16x16x32_bf16(curA[kc], bf1, acc1, 0, 0, 0);
        }

        // epilogue: tanh * w * embed; 16-row in-tile suffix
        float wmr[4], iv[4];
        #pragma unroll
        for (int r = 0; r < 4; ++r) {
            wmr[r] = wsLds[c * CH_ + wv * 16 + q * 4 + r];
            iv[r]  = ivLds[c * CH_ + wv * 16 + q * 4 + r];
        }
        float sv0[4], sv1[4];
        {
            float tv[4];
            #pragma unroll
            for (int r = 0; r < 4; ++r) {
                float x = acc0[r] + bb0;
                x = fminf(fmaxf(x, -15.f), 15.f);
                float ex = __expf(2.f * x);
                tv[r] = wmr[r] * ((ex - 1.f) / (ex + 1.f)) * eUse0[r];
            }
            float s3 = tv[3], s2 = tv[2] + s3, s1 = tv[1] + s2, s0 = tv[0] + s1;
            float g = s0;
            float g1 = __shfl_down(g, 16, 64);
            float g2 = __shfl_down(g, 32, 64);
            float g3 = __shfl_down(g, 48, 64);
            float addG = (q < 3 ? g1 : 0.f) + (q < 2 ? g2 : 0.f) + (q < 1 ? g3 : 0.f);
            if (q == 0) red[rb][wv * EG_ + l15] = g + addG;
            sv0[0] = s0 + addG; sv0[1] = s1 + addG;
            sv0[2] = s2 + addG; sv0[3] = s3 + addG;
        }
        {
            float tv[4];
            #pragma unroll
            for (int r = 0; r < 4; ++r) {
                float x = acc1[r] + bb1;
                x = fminf(fmaxf(x, -15.f), 15.f);
                float ex = __expf(2.f * x);
                tv[r] = wmr[r] * ((ex - 1.f) / (ex + 1.f)) * eUse1[r];
            }
            float s3 = tv[3], s2 = tv[2] + s3, s1 = tv[1] + s2, s0 = tv[0] + s1;
            float g = s0;
            float g1 = __shfl_down(g, 16, 64);
            float g2 = __shfl_down(g, 32, 64);
            float g3 = __shfl_down(g, 48, 64);
            float addG = (q < 3 ? g1 : 0.f) + (q < 2 ? g2 : 0.f) + (q < 1 ? g3 : 0.f);
            if (q == 0) red[rb][wv * EG_ + 16 + l15] = g + addG;
            sv1[0] = s0 + addG; sv1[1] = s1 + addG;
            sv1[2] = s2 + addG; sv1[3] = s3 + addG;
        }

        // LIGHT barrier: drain LDS only; A/embed prefetch + t stores keep flying
        asm volatile("s_waitcnt lgkmcnt(0)" ::: "memory");
        __builtin_amdgcn_s_barrier();
        __builtin_amdgcn_sched_barrier(0);

        float nr0, nr1, later0, later1;
        {
            const float rn = run[rb][l15];
            float later = rn, tot = 0.f;
            #pragma unroll
            for (int w2 = 0; w2 < 8; ++w2) {
                float v = red[rb][w2 * EG_ + l15];
                tot += v;
                if (w2 > wv) later += v;
            }
            nr0 = rn + tot; later0 = later;
        }
        {
            const float rn = run[rb][16 + l15];
            float later = rn, tot = 0.f;
            #pragma unroll
            for (int w2 = 0; w2 < 8; ++w2) {
                float v = red[rb][w2 * EG_ + 16 + l15];
                tot += v;
                if (w2 > wv) later += v;
            }
            nr1 = rn + tot; later1 = later;
        }

        // final values -> wave-private stg -> coalesced dwordx4 stores
        #pragma unroll
        for (int r = 0; r < 4; ++r) {
            stg[wv][q * 4 + r][l15]      = (sv0[r] + later0) * iv[r];
            stg[wv][q * 4 + r][16 + l15] = (sv1[r] + later1) * iv[r];
        }
        asm volatile("s_waitcnt lgkmcnt(0)" ::: "memory");
        {
            float4 o0 = *(const float4*)(&stg[wv][orow][oc8]);
            float4 o1 = *(const float4*)(&stg[wv][orow][oc8 + 4]);
            float* dst = Tg + ((size_t)c * CH_ + orow) * E_ + oc8;
            *(float4*)(dst)     = o0;
            *(float4*)(dst + 4) = o1;
        }

        if (wv == 0 && q == 0) {        // next chunk's carry (other buffer)
            run[rb ^ 1][l15] = nr0;
            run[rb ^ 1][16 + l15] = nr1;
        }
        // next chunk's barrier orders this write before its readers
    }
}

extern "C" void kernel_launch(void* const* d_in, const int* in_sizes, int n_in,
                              void* d_out, int out_size, void* d_ws, size_t ws_size,
                              hipStream_t stream) {
    const float* alpha = (const float*)d_in[0];
    const float* beta  = (const float*)d_in[1];
    const float* embed = (const float*)d_in[2];
    const float* mask  = (const float*)d_in[3];
    const float* Wb    = (const float*)d_in[4];
    const float* bbp   = (const float*)d_in[5];
    const float* Wa    = (const float*)d_in[6];
    const float* bap   = (const float*)d_in[7];

    char* ws = (char*)d_ws;
    float*  w      = (float*)ws;                       // 256 KB
    __bf16* WbBf   = (__bf16*)(ws + (256 << 10));      // 128 KB
    __bf16* betaBf = (__bf16*)(ws + (512 << 10));      // 32 MB  (proven to fit, R10)

    k0_prep<<<1024, 256, 0, stream>>>(alpha, mask, Wa, bap, Wb, beta,
                                      WbBf, betaBf, w);
    k2_bf<<<B_ * (E_ / EG_), 512, 0, stream>>>(betaBf, embed, WbBf, bbp, w,
                                               (float*)d_out);
}